// Round 2
// 981.966 us; speedup vs baseline: 4.0355x; 4.0355x over previous
//
#include <hip/hip_runtime.h>
#include <hip/hip_bf16.h>
#include <math.h>

constexpr int BATCH = 8;
constexpr int IMG_H = 64;
constexpr int IMG_W = 512;
constexpr int DIM   = 128;
constexpr int WIN_H = 4, WIN_W = 32;
constexpr int SHIFT_H = 2, SHIFT_W = 2;
constexpr int NTOK = 128;            // tokens per window
constexpr int HEADS = 4, HD = 32;
constexpr float QK_SCALE = 0.17677669529663687f;   // 1/sqrt(32)

typedef __attribute__((ext_vector_type(8))) short bf16x8;
typedef __attribute__((ext_vector_type(4))) float f32x4;

__device__ __forceinline__ unsigned short f2bf(float f) {
    unsigned u = __float_as_uint(f);
    u = (u + 0x7fffu + ((u >> 16) & 1u)) >> 16;   // RNE
    return (unsigned short)u;
}

// XOR-swizzled index into a [128][128] bf16 LDS tile (T2, breaks the
// stride-256B 32-way bank conflict on ds_read_b128). 16B-chunk safe:
// cols that share bits>=3 stay contiguous.
__device__ __forceinline__ int sc(int r, int c) {
    return (r << 7) + (c ^ ((r & 7) << 3));
}

// ---------------------------------------------------------------------------
// Kernel 0: convert weights to bf16, transposed (B^T layout for b-frags).
// w1t[n][k]    = fc1_w[k][n]   (n<512, k<128)
// w2t[n][k]    = fc2_w[k][n]   (n<128, k<512)
// qkv_wt[n][k] = qkv_w[k][n]   (n<384, k<128), Q rows (n<128) pre-scaled
// proj_wt[n][k]= proj_w[k][n]  (n<128, k<128)
// ---------------------------------------------------------------------------
__global__ __launch_bounds__(256) void prep_weights(
    const float* __restrict__ fc1_w, const float* __restrict__ fc2_w,
    const float* __restrict__ qkv_w, const float* __restrict__ proj_w,
    unsigned short* __restrict__ w1t, unsigned short* __restrict__ w2t,
    unsigned short* __restrict__ qkv_wt, unsigned short* __restrict__ proj_wt)
{
    const int tid = blockIdx.x * 256 + threadIdx.x;
    if (tid < 512 * 128) {
        const int n = tid >> 7, k = tid & 127;
        w1t[tid] = f2bf(fc1_w[k * 512 + n]);
    } else if (tid < 2 * 512 * 128) {
        const int t = tid - 512 * 128;
        const int n = t >> 9, k = t & 511;
        w2t[t] = f2bf(fc2_w[k * 128 + n]);
    } else if (tid < 2 * 512 * 128 + 384 * 128) {
        const int t = tid - 2 * 512 * 128;
        const int n = t >> 7, k = t & 127;
        float v = qkv_w[k * 384 + n];
        if (n < 128) v *= QK_SCALE;      // fold softmax scale into Wq
        qkv_wt[t] = f2bf(v);
    } else if (tid < 2 * 512 * 128 + 384 * 128 + 128 * 128) {
        const int t = tid - (2 * 512 * 128 + 384 * 128);
        const int n = t >> 7, k = t & 127;
        proj_wt[t] = f2bf(proj_w[k * 128 + n]);
    }
}

// ---------------------------------------------------------------------------
// Kernel 1: LN1 + cyclic shift + window attention + proj + residual, MFMA.
// One window (128 tokens) per block, 256 threads = 4 waves.
// Wave wv owns token rows 32*wv..32*wv+31 for LN, QKV-A, QK rows, P rows,
// PV rows, proj rows and the epilogue -> exactly ONE __syncthreads().
// ---------------------------------------------------------------------------
__global__ __launch_bounds__(256, 1) void swin_attn_mfma(
    const float* __restrict__ x,
    const float* __restrict__ g1,
    const float* __restrict__ b1,
    const unsigned short* __restrict__ qkv_wt,   // [384][128] bf16 (Q scaled)
    const float* __restrict__ qkv_b,
    const float* __restrict__ rpb,
    const unsigned short* __restrict__ proj_wt,  // [128][128] bf16
    const float* __restrict__ proj_b,
    float* __restrict__ out)
{
    __shared__ __align__(16) unsigned short s_xw[128 * 128]; // LN'd x; later P/O scratch
    __shared__ __align__(16) unsigned short s_q [128 * 128]; // Q (scaled) [t][d]
    __shared__ __align__(16) unsigned short s_k [128 * 128]; // K [t][d]
    __shared__ __align__(16) unsigned short s_vt[128 * 128]; // V^T [d][t]
    __shared__ float s_rpb[441 * 4];

    const int tid = threadIdx.x;
    const int wv  = tid >> 6;
    const int ln  = tid & 63;
    const int g   = ln >> 4;          // 0..3
    const int c15 = ln & 15;          // frag row/col lane index
    const int kq  = g * 8;            // k offset (shorts) for a/b frags
    const int qr0 = wv * 32;          // wave-owned token rows

    const int b   = blockIdx.x >> 8;
    const int wid = blockIdx.x & 255;
    const int wp  = wid >> 4;
    const int wq  = wid & 15;

    // ---- Phase 0: LN1 + shift -> s_xw (bf16). Half-wave per token. ----
    {
        const int lh = ln & 31;
        const int hf = ln >> 5;
        const float4 gv = *(const float4*)&g1[lh * 4];
        const float4 bv = *(const float4*)&b1[lh * 4];
        #pragma unroll
        for (int it = 0; it < 16; ++it) {
            const int t  = qr0 + it * 2 + hf;
            const int th = t >> 5, tw = t & 31;
            const int gh = (wp * WIN_H + th + SHIFT_H) & (IMG_H - 1);
            const int gw = (wq * WIN_W + tw + SHIFT_W) & (IMG_W - 1);
            const float4 v = *(const float4*)&x[((((size_t)b * IMG_H + gh) * IMG_W + gw) * DIM) + lh * 4];
            float s  = v.x + v.y + v.z + v.w;
            float s2 = v.x * v.x + v.y * v.y + v.z * v.z + v.w * v.w;
            #pragma unroll
            for (int off = 1; off < 32; off <<= 1) {
                s  += __shfl_xor(s, off);
                s2 += __shfl_xor(s2, off);
            }
            const float mean = s * (1.0f / 128.0f);
            const float rs   = rsqrtf(s2 * (1.0f / 128.0f) - mean * mean + 1e-5f);
            const unsigned short o0 = f2bf((v.x - mean) * rs * gv.x + bv.x);
            const unsigned short o1 = f2bf((v.y - mean) * rs * gv.y + bv.y);
            const unsigned short o2 = f2bf((v.z - mean) * rs * gv.z + bv.z);
            const unsigned short o3 = f2bf((v.w - mean) * rs * gv.w + bv.w);
            uint2 pk;
            pk.x = (unsigned)o0 | ((unsigned)o1 << 16);
            pk.y = (unsigned)o2 | ((unsigned)o3 << 16);
            *(uint2*)&s_xw[sc(t, lh * 4)] = pk;
        }
    }

    // stage rpb (all heads) into LDS (covered by the single barrier below)
    for (int i = tid; i < 441 * 4; i += 256) s_rpb[i] = rpb[i];

    // ---- Phase 1: QKV = xw @ Wqkv. Wave computes its 32 rows x all 384. ----
    {
        bf16x8 afr[2][4];
        #pragma unroll
        for (int rt = 0; rt < 2; ++rt)
            #pragma unroll
            for (int ks = 0; ks < 4; ++ks)
                afr[rt][ks] = *(const bf16x8*)&s_xw[sc(qr0 + rt * 16 + c15, ks * 32 + kq)];

        bf16x8 bfr[4];
        #pragma unroll
        for (int ks = 0; ks < 4; ++ks)
            bfr[ks] = *(const bf16x8*)&qkv_wt[(size_t)c15 * 128 + ks * 32 + kq];
        float bias = qkv_b[c15] * QK_SCALE;

        for (int ct = 0; ct < 24; ++ct) {
            // prefetch next col-tile's b-frags + bias (dummy reload of tile 0 at end)
            const int ctn = (ct < 23) ? ct + 1 : 0;
            const int nn  = ctn * 16 + c15;
            bf16x8 bnx[4];
            #pragma unroll
            for (int ks = 0; ks < 4; ++ks)
                bnx[ks] = *(const bf16x8*)&qkv_wt[(size_t)nn * 128 + ks * 32 + kq];
            const float biasn = qkv_b[nn] * ((ctn < 8) ? QK_SCALE : 1.0f);

            f32x4 ac0 = (f32x4){0.f, 0.f, 0.f, 0.f};
            f32x4 ac1 = (f32x4){0.f, 0.f, 0.f, 0.f};
            #pragma unroll
            for (int ks = 0; ks < 4; ++ks) {
                ac0 = __builtin_amdgcn_mfma_f32_16x16x32_bf16(afr[0][ks], bfr[ks], ac0, 0, 0, 0);
                ac1 = __builtin_amdgcn_mfma_f32_16x16x32_bf16(afr[1][ks], bfr[ks], ac1, 0, 0, 0);
            }

            const int part = ct >> 3;          // 0=Q 1=K 2=V
            const int dc   = (ct & 7) * 16;    // col within part
            #pragma unroll
            for (int rt = 0; rt < 2; ++rt) {
                const f32x4 ac = rt ? ac1 : ac0;
                #pragma unroll
                for (int r = 0; r < 4; ++r) {
                    const int t = qr0 + rt * 16 + g * 4 + r;
                    const unsigned short hv = f2bf(ac[r] + bias);
                    if (part == 0)      s_q [sc(t, dc + c15)] = hv;
                    else if (part == 1) s_k [sc(t, dc + c15)] = hv;
                    else                s_vt[sc(dc + c15, t)] = hv;  // transposed
                }
            }
            #pragma unroll
            for (int ks = 0; ks < 4; ++ks) bfr[ks] = bnx[ks];
            bias = biasn;
        }
    }

    __syncthreads();   // the only barrier: K/V/rpb become visible cross-wave

    // ---- per-lane head-invariant column info (j = jt*16 + c15) ----
    int colterm[8], rgj[8];
    #pragma unroll
    for (int jt = 0; jt < 8; ++jt) {
        const int j  = jt * 16 + c15;
        const int jh = j >> 5, jw = j & 31;
        colterm[jt] = jh * 63 + jw;
        const int gh1 = wp * WIN_H + jh, gw1 = wq * WIN_W + jw;
        rgj[jt] = ((gh1 < IMG_H - WIN_H) ? 0 : (gh1 < IMG_H - SHIFT_H ? 1 : 2)) * 3
                + ((gw1 < IMG_W - WIN_W) ? 0 : (gw1 < IMG_W - SHIFT_W ? 1 : 2));
    }

    f32x4 acc_out[2][8];
    #pragma unroll
    for (int rt = 0; rt < 2; ++rt)
        #pragma unroll
        for (int n = 0; n < 8; ++n) acc_out[rt][n] = (f32x4){0.f, 0.f, 0.f, 0.f};

    // ---- Phase 2: per head: QK^T -> softmax -> PV -> partial proj ----
    for (int h = 0; h < 4; ++h) {
        bf16x8 bk[8];
        #pragma unroll
        for (int jt = 0; jt < 8; ++jt)
            bk[jt] = *(const bf16x8*)&s_k[sc(jt * 16 + c15, h * 32 + kq)];

        #pragma unroll
        for (int rt = 0; rt < 2; ++rt) {
            const bf16x8 aq = *(const bf16x8*)&s_q[sc(qr0 + rt * 16 + c15, h * 32 + kq)];
            f32x4 sacc[8];
            #pragma unroll
            for (int jt = 0; jt < 8; ++jt)
                sacc[jt] = __builtin_amdgcn_mfma_f32_16x16x32_bf16(
                    aq, bk[jt], (f32x4){0.f, 0.f, 0.f, 0.f}, 0, 0, 0);

            // bias + mask + row softmax; rows of this lane: g*4 + r
            #pragma unroll
            for (int r = 0; r < 4; ++r) {
                const int q  = qr0 + rt * 16 + g * 4 + r;
                const int qh = q >> 5, qw = q & 31;
                const int rowterm = (qh + 3) * 63 + qw + 31;
                const int gh0 = wp * WIN_H + qh, gw0 = wq * WIN_W + qw;
                const int rgq = ((gh0 < IMG_H - WIN_H) ? 0 : (gh0 < IMG_H - SHIFT_H ? 1 : 2)) * 3
                              + ((gw0 < IMG_W - WIN_W) ? 0 : (gw0 < IMG_W - SHIFT_W ? 1 : 2));
                float vals[8];
                float mx = -1e30f;
                #pragma unroll
                for (int jt = 0; jt < 8; ++jt) {
                    float a = sacc[jt][r] + s_rpb[(rowterm - colterm[jt]) * 4 + h];
                    a = (rgj[jt] != rgq) ? a - 100.f : a;
                    vals[jt] = a;
                    mx = fmaxf(mx, a);
                }
                #pragma unroll
                for (int off = 1; off < 16; off <<= 1) mx = fmaxf(mx, __shfl_xor(mx, off));
                float den = 0.f;
                #pragma unroll
                for (int jt = 0; jt < 8; ++jt) {
                    vals[jt] = exp2f((vals[jt] - mx) * 1.44269504f);
                    den += vals[jt];
                }
                #pragma unroll
                for (int off = 1; off < 16; off <<= 1) den += __shfl_xor(den, off);
                const float inv = 1.0f / den;
                #pragma unroll
                for (int jt = 0; jt < 8; ++jt)
                    s_xw[sc(q, jt * 16 + c15)] = f2bf(vals[jt] * inv);  // P, wave-private rows
            }
        }

        // PV: O(32x32) = P(32x128) @ V(128x32)
        f32x4 ao[2][2];
        #pragma unroll
        for (int rt = 0; rt < 2; ++rt)
            #pragma unroll
            for (int ct2 = 0; ct2 < 2; ++ct2) ao[rt][ct2] = (f32x4){0.f, 0.f, 0.f, 0.f};
        #pragma unroll
        for (int ks = 0; ks < 4; ++ks) {
            const bf16x8 ap0 = *(const bf16x8*)&s_xw[sc(qr0 + c15,      ks * 32 + kq)];
            const bf16x8 ap1 = *(const bf16x8*)&s_xw[sc(qr0 + 16 + c15, ks * 32 + kq)];
            const bf16x8 bv0 = *(const bf16x8*)&s_vt[sc(h * 32 + c15,      ks * 32 + kq)];
            const bf16x8 bv1 = *(const bf16x8*)&s_vt[sc(h * 32 + 16 + c15, ks * 32 + kq)];
            ao[0][0] = __builtin_amdgcn_mfma_f32_16x16x32_bf16(ap0, bv0, ao[0][0], 0, 0, 0);
            ao[0][1] = __builtin_amdgcn_mfma_f32_16x16x32_bf16(ap0, bv1, ao[0][1], 0, 0, 0);
            ao[1][0] = __builtin_amdgcn_mfma_f32_16x16x32_bf16(ap1, bv0, ao[1][0], 0, 0, 0);
            ao[1][1] = __builtin_amdgcn_mfma_f32_16x16x32_bf16(ap1, bv1, ao[1][1], 0, 0, 0);
        }

        // stage O (bf16) into cols 0..31 of own rows (P fully consumed)
        #pragma unroll
        for (int rt = 0; rt < 2; ++rt)
            #pragma unroll
            for (int ct2 = 0; ct2 < 2; ++ct2)
                #pragma unroll
                for (int r = 0; r < 4; ++r)
                    s_xw[sc(qr0 + rt * 16 + g * 4 + r, ct2 * 16 + c15)] = f2bf(ao[rt][ct2][r]);

        // partial proj: acc_out += O_h(32x32) @ proj_w[h*32..+32][:]
        const bf16x8 aO0 = *(const bf16x8*)&s_xw[sc(qr0 + c15,      kq)];
        const bf16x8 aO1 = *(const bf16x8*)&s_xw[sc(qr0 + 16 + c15, kq)];
        #pragma unroll
        for (int ct8 = 0; ct8 < 8; ++ct8) {
            const bf16x8 bw = *(const bf16x8*)&proj_wt[(size_t)(ct8 * 16 + c15) * 128 + h * 32 + kq];
            acc_out[0][ct8] = __builtin_amdgcn_mfma_f32_16x16x32_bf16(aO0, bw, acc_out[0][ct8], 0, 0, 0);
            acc_out[1][ct8] = __builtin_amdgcn_mfma_f32_16x16x32_bf16(aO1, bw, acc_out[1][ct8], 0, 0, 0);
        }
    }

    // ---- epilogue: out = x + proj(o) + proj_b, reverse shift ----
    #pragma unroll
    for (int ct8 = 0; ct8 < 8; ++ct8) {
        const float pb = proj_b[ct8 * 16 + c15];
        #pragma unroll
        for (int rt = 0; rt < 2; ++rt)
            #pragma unroll
            for (int r = 0; r < 4; ++r) {
                const int t  = qr0 + rt * 16 + g * 4 + r;
                const int th = t >> 5, tw = t & 31;
                const int gh = (wp * WIN_H + th + SHIFT_H) & (IMG_H - 1);
                const int gw = (wq * WIN_W + tw + SHIFT_W) & (IMG_W - 1);
                const size_t gi = (((size_t)b * IMG_H + gh) * IMG_W + gw) * DIM + ct8 * 16 + c15;
                out[gi] = x[gi] + acc_out[rt][ct8][r] + pb;
            }
    }
}

// ---------------------------------------------------------------------------
// Kernel 2: LN2 + MLP via MFMA. 64 tokens/block, 256 threads (4 waves),
// hidden processed in 8 chunks of 64. (unchanged, verified in round 0)
// ---------------------------------------------------------------------------
__global__ __launch_bounds__(256) void swin_mlp_mfma(
    const float* __restrict__ g2, const float* __restrict__ beta2,
    const unsigned short* __restrict__ w1t,   // [512][128] bf16 (fc1_w^T)
    const float* __restrict__ fc1_b,
    const unsigned short* __restrict__ w2t,   // [128][512] bf16 (fc2_w^T)
    const float* __restrict__ fc2_b,
    float* __restrict__ out)
{
    __shared__ __align__(16) unsigned short s_x[64][136];    // LN'd tokens [m][k]
    __shared__ __align__(16) unsigned short s_h[64][72];     // hidden chunk [m][k]
    __shared__ __align__(16) unsigned short s_w1[64][136];   // w1 chunk B^T [n][k]
    __shared__ __align__(16) unsigned short s_w2[128][72];   // w2 chunk B^T [n][k]

    const int tid = threadIdx.x;
    const int wv  = tid >> 6;
    const int ln  = tid & 63;
    const int m0  = wv * 16;                 // wave-owned token rows
    const size_t tok0 = (size_t)blockIdx.x * 64;

    // ---- LN2: each half-wave handles one token (32 lanes x float4) ----
    {
        const int lh = ln & 31;
        const int hf = ln >> 5;
        const float4 gv = *(const float4*)&g2[lh * 4];
        const float4 bv = *(const float4*)&beta2[lh * 4];
        for (int it = 0; it < 8; ++it) {
            const int t = m0 + it * 2 + hf;
            const float4 v = *(const float4*)&out[(tok0 + t) * 128 + lh * 4];
            float s  = v.x + v.y + v.z + v.w;
            float s2 = v.x * v.x + v.y * v.y + v.z * v.z + v.w * v.w;
            #pragma unroll
            for (int off = 1; off < 32; off <<= 1) {
                s  += __shfl_xor(s, off);
                s2 += __shfl_xor(s2, off);
            }
            const float mean = s * (1.0f / 128.0f);
            const float var  = s2 * (1.0f / 128.0f) - mean * mean;
            const float rs   = rsqrtf(var + 1e-5f);
            const unsigned short o0 = f2bf((v.x - mean) * rs * gv.x + bv.x);
            const unsigned short o1 = f2bf((v.y - mean) * rs * gv.y + bv.y);
            const unsigned short o2 = f2bf((v.z - mean) * rs * gv.z + bv.z);
            const unsigned short o3 = f2bf((v.w - mean) * rs * gv.w + bv.w);
            uint2 pk;
            pk.x = (unsigned)o0 | ((unsigned)o1 << 16);
            pk.y = (unsigned)o2 | ((unsigned)o3 << 16);
            *(uint2*)&s_x[t][lh * 4] = pk;
        }
    }

    f32x4 acc_o[8];
    #pragma unroll
    for (int i = 0; i < 8; ++i) acc_o[i] = (f32x4){0.f, 0.f, 0.f, 0.f};

    const int ar = m0 + (ln & 15);          // a-frag row
    const int nr = ln & 15;                 // b-frag n within tile
    const int kq = (ln >> 4) * 8;           // k quad offset
    const int dr = m0 + (ln >> 4) * 4;      // D-frag row base

    for (int c = 0; c < 8; ++c) {
        for (int j = tid; j < 1024; j += 256) {
            const int row = j >> 4, c8 = j & 15;
            *(uint4*)&s_w1[row][c8 * 8] = *(const uint4*)&w1t[(size_t)(c * 64 + row) * 128 + c8 * 8];
        }
        for (int j = tid; j < 1024; j += 256) {
            const int row = j >> 3, c8 = j & 7;
            *(uint4*)&s_w2[row][c8 * 8] = *(const uint4*)&w2t[(size_t)row * 512 + c * 64 + c8 * 8];
        }
        __syncthreads();
        // GEMM1: h(16x64 per wave) = x_ln(16x128) @ w1c(128x64)
        f32x4 hA[4];
        #pragma unroll
        for (int i = 0; i < 4; ++i) hA[i] = (f32x4){0.f, 0.f, 0.f, 0.f};
        #pragma unroll
        for (int ks = 0; ks < 4; ++ks) {
            const bf16x8 a = *(const bf16x8*)&s_x[ar][ks * 32 + kq];
            #pragma unroll
            for (int nt = 0; nt < 4; ++nt) {
                const bf16x8 bb = *(const bf16x8*)&s_w1[nt * 16 + nr][ks * 32 + kq];
                hA[nt] = __builtin_amdgcn_mfma_f32_16x16x32_bf16(a, bb, hA[nt], 0, 0, 0);
            }
        }
        // bias + exact GELU, write hidden chunk (wave-private rows)
        #pragma unroll
        for (int nt = 0; nt < 4; ++nt) {
            const float bias = fc1_b[c * 64 + nt * 16 + nr];
            #pragma unroll
            for (int r = 0; r < 4; ++r) {
                float v = hA[nt][r] + bias;
                v = 0.5f * v * (1.0f + erff(v * 0.70710678118654752f));
                s_h[dr + r][nt * 16 + nr] = f2bf(v);
            }
        }
        __syncthreads();
        // GEMM2: acc_o += h(16x64) @ w2c(64x128)
        #pragma unroll
        for (int ks = 0; ks < 2; ++ks) {
            const bf16x8 a = *(const bf16x8*)&s_h[ar][ks * 32 + kq];
            #pragma unroll
            for (int nt = 0; nt < 8; ++nt) {
                const bf16x8 bb = *(const bf16x8*)&s_w2[nt * 16 + nr][ks * 32 + kq];
                acc_o[nt] = __builtin_amdgcn_mfma_f32_16x16x32_bf16(a, bb, acc_o[nt], 0, 0, 0);
            }
        }
        __syncthreads();
    }

    // ---- epilogue: out += mlp(out_ln) + fc2_b  (residual re-read, L2-hot) ----
    #pragma unroll
    for (int nt = 0; nt < 8; ++nt) {
        const float bias = fc2_b[nt * 16 + nr];
        #pragma unroll
        for (int r = 0; r < 4; ++r) {
            const size_t gi = (tok0 + dr + r) * 128 + nt * 16 + nr;
            out[gi] = out[gi] + acc_o[nt][r] + bias;
        }
    }
}

extern "C" void kernel_launch(void* const* d_in, const int* in_sizes, int n_in,
                              void* d_out, int out_size, void* d_ws, size_t ws_size,
                              hipStream_t stream) {
    (void)in_sizes; (void)n_in; (void)out_size;
    const float* x      = (const float*)d_in[0];
    const float* g1     = (const float*)d_in[1];
    const float* b1     = (const float*)d_in[2];
    const float* qkv_w  = (const float*)d_in[3];
    const float* qkv_b  = (const float*)d_in[4];
    const float* rpb    = (const float*)d_in[5];
    const float* proj_w = (const float*)d_in[6];
    const float* proj_b = (const float*)d_in[7];
    const float* g2     = (const float*)d_in[8];
    const float* bb2    = (const float*)d_in[9];
    const float* fc1_w  = (const float*)d_in[10];
    const float* fc1_b  = (const float*)d_in[11];
    const float* fc2_w  = (const float*)d_in[12];
    const float* fc2_b  = (const float*)d_in[13];

    // Workspace layout (bf16 shorts): w1t | w2t | qkv_wt | proj_wt
    const size_t ws_needed = (size_t)(2 * 512 * 128 + 384 * 128 + 128 * 128)
                           * sizeof(unsigned short);   // 384 KiB
    if (ws_size != 0 && ws_size < ws_needed) {
        // Diagnostic hedge: fail cleanly (wrong output) instead of corrupting
        // memory beyond the workspace and killing the container.
        return;
    }

    unsigned short* w1t     = (unsigned short*)d_ws;             // 512*128 bf16
    unsigned short* w2t     = w1t + 512 * 128;                   // 128*512 bf16
    unsigned short* qkv_wt  = w2t + 512 * 128;                   // 384*128 bf16
    unsigned short* proj_wt = qkv_wt + 384 * 128;                // 128*128 bf16

    hipLaunchKernelGGL(prep_weights, dim3(768), dim3(256), 0, stream,
                       fc1_w, fc2_w, qkv_w, proj_w, w1t, w2t, qkv_wt, proj_wt);
    hipLaunchKernelGGL(swin_attn_mfma, dim3(BATCH * 256), dim3(256), 0, stream,
                       x, g1, b1, qkv_wt, qkv_b, rpb, proj_wt, proj_b, (float*)d_out);
    hipLaunchKernelGGL(swin_mlp_mfma, dim3(BATCH * IMG_H * IMG_W / 64), dim3(256), 0, stream,
                       g2, bb2, w1t, fc1_b, w2t, fc2_b, (float*)d_out);
}

// Round 3
// 838.265 us; speedup vs baseline: 4.7272x; 1.1714x over previous
//
#include <hip/hip_runtime.h>
#include <hip/hip_bf16.h>
#include <math.h>

constexpr int BATCH = 8;
constexpr int IMG_H = 64;
constexpr int IMG_W = 512;
constexpr int DIM   = 128;
constexpr int WIN_H = 4, WIN_W = 32;
constexpr int SHIFT_H = 2, SHIFT_W = 2;
constexpr int NTOK = 128;            // tokens per window
constexpr int HEADS = 4, HD = 32;
constexpr float QK_SCALE = 0.17677669529663687f;   // 1/sqrt(32)

typedef __attribute__((ext_vector_type(8))) short bf16x8;
typedef __attribute__((ext_vector_type(4))) float f32x4;

__device__ __forceinline__ unsigned short f2bf(float f) {
    unsigned u = __float_as_uint(f);
    u = (u + 0x7fffu + ((u >> 16) & 1u)) >> 16;   // RNE
    return (unsigned short)u;
}

// XOR-swizzled index into a [128][128] bf16 LDS tile (T2, breaks the
// stride-256B 32-way bank conflict on ds_read_b128). 16B-chunk safe.
__device__ __forceinline__ int sc(int r, int c) {
    return (r << 7) + (c ^ ((r & 7) << 3));
}

// tanh-form GELU: 0.5v(1+tanh(0.79788456(v+0.044715 v^3))) = v*sigmoid(2u).
// Max |err| vs exact erf-GELU ~4e-4 for |v|<4 -> below bf16 rounding noise.
__device__ __forceinline__ float gelu_tanh(float v) {
    const float u = v * (0.7978845608028654f + 0.035677408136300125f * v * v);
    const float e = exp2f(u * -2.8853900817779268f);   // exp(-2u)
    return v * __builtin_amdgcn_rcpf(1.0f + e);
}

// ---------------------------------------------------------------------------
// Kernel 0: convert weights to bf16, transposed (B^T layout for b-frags).
// ---------------------------------------------------------------------------
__global__ __launch_bounds__(256) void prep_weights(
    const float* __restrict__ fc1_w, const float* __restrict__ fc2_w,
    const float* __restrict__ qkv_w, const float* __restrict__ proj_w,
    unsigned short* __restrict__ w1t, unsigned short* __restrict__ w2t,
    unsigned short* __restrict__ qkv_wt, unsigned short* __restrict__ proj_wt)
{
    const int tid = blockIdx.x * 256 + threadIdx.x;
    if (tid < 512 * 128) {
        const int n = tid >> 7, k = tid & 127;
        w1t[tid] = f2bf(fc1_w[k * 512 + n]);
    } else if (tid < 2 * 512 * 128) {
        const int t = tid - 512 * 128;
        const int n = t >> 9, k = t & 511;
        w2t[t] = f2bf(fc2_w[k * 128 + n]);
    } else if (tid < 2 * 512 * 128 + 384 * 128) {
        const int t = tid - 2 * 512 * 128;
        const int n = t >> 7, k = t & 127;
        float v = qkv_w[k * 384 + n];
        if (n < 128) v *= QK_SCALE;      // fold softmax scale into Wq
        qkv_wt[t] = f2bf(v);
    } else if (tid < 2 * 512 * 128 + 384 * 128 + 128 * 128) {
        const int t = tid - (2 * 512 * 128 + 384 * 128);
        const int n = t >> 7, k = t & 127;
        proj_wt[t] = f2bf(proj_w[k * 128 + n]);
    }
}

// ---------------------------------------------------------------------------
// Kernel 1: LN1 + cyclic shift + window attention + proj + residual, MFMA.
// One window (128 tokens) per block, 512 threads = 8 waves (2 waves/SIMD).
// Wave wv owns token rows 16*wv..16*wv+15 end-to-end -> one __syncthreads().
// ---------------------------------------------------------------------------
__global__ __launch_bounds__(512, 2) void swin_attn_mfma(
    const float* __restrict__ x,
    const float* __restrict__ g1,
    const float* __restrict__ b1,
    const unsigned short* __restrict__ qkv_wt,   // [384][128] bf16 (Q scaled)
    const float* __restrict__ qkv_b,
    const float* __restrict__ rpb,
    const unsigned short* __restrict__ proj_wt,  // [128][128] bf16
    const float* __restrict__ proj_b,
    float* __restrict__ out)
{
    __shared__ __align__(16) unsigned short s_xw[128 * 128]; // LN'd x; later P/O scratch
    __shared__ __align__(16) unsigned short s_q [128 * 128]; // Q (scaled) [t][d]
    __shared__ __align__(16) unsigned short s_k [128 * 128]; // K [t][d]
    __shared__ __align__(16) unsigned short s_vt[128 * 128]; // V^T [d][t]
    __shared__ float s_rpb[441 * 4];

    const int tid = threadIdx.x;
    const int wv  = tid >> 6;         // 0..7
    const int ln  = tid & 63;
    const int g   = ln >> 4;          // 0..3
    const int c15 = ln & 15;          // frag row/col lane index
    const int kq  = g * 8;            // k offset (shorts) for a/b frags
    const int qr0 = wv * 16;          // wave-owned token rows (16 each)

    const int b   = blockIdx.x >> 8;
    const int wid = blockIdx.x & 255;
    const int wp  = wid >> 4;
    const int wq  = wid & 15;

    // ---- Phase 0: LN1 + shift -> s_xw (bf16). Half-wave per token. ----
    {
        const int lh = ln & 31;
        const int hf = ln >> 5;
        const float4 gv = *(const float4*)&g1[lh * 4];
        const float4 bv = *(const float4*)&b1[lh * 4];
        #pragma unroll
        for (int it = 0; it < 8; ++it) {
            const int t  = qr0 + it * 2 + hf;
            const int th = t >> 5, tw = t & 31;
            const int gh = (wp * WIN_H + th + SHIFT_H) & (IMG_H - 1);
            const int gw = (wq * WIN_W + tw + SHIFT_W) & (IMG_W - 1);
            const float4 v = *(const float4*)&x[((((size_t)b * IMG_H + gh) * IMG_W + gw) * DIM) + lh * 4];
            float s  = v.x + v.y + v.z + v.w;
            float s2 = v.x * v.x + v.y * v.y + v.z * v.z + v.w * v.w;
            #pragma unroll
            for (int off = 1; off < 32; off <<= 1) {
                s  += __shfl_xor(s, off);
                s2 += __shfl_xor(s2, off);
            }
            const float mean = s * (1.0f / 128.0f);
            const float rs   = rsqrtf(s2 * (1.0f / 128.0f) - mean * mean + 1e-5f);
            const unsigned short o0 = f2bf((v.x - mean) * rs * gv.x + bv.x);
            const unsigned short o1 = f2bf((v.y - mean) * rs * gv.y + bv.y);
            const unsigned short o2 = f2bf((v.z - mean) * rs * gv.z + bv.z);
            const unsigned short o3 = f2bf((v.w - mean) * rs * gv.w + bv.w);
            uint2 pk;
            pk.x = (unsigned)o0 | ((unsigned)o1 << 16);
            pk.y = (unsigned)o2 | ((unsigned)o3 << 16);
            *(uint2*)&s_xw[sc(t, lh * 4)] = pk;
        }
    }

    // stage rpb (all heads) into LDS (covered by the single barrier below)
    for (int i = tid; i < 441 * 4; i += 512) s_rpb[i] = rpb[i];

    // ---- Phase 1: QKV = xw @ Wqkv. Wave computes its 16 rows x all 384. ----
    {
        bf16x8 afr[4];
        #pragma unroll
        for (int ks = 0; ks < 4; ++ks)
            afr[ks] = *(const bf16x8*)&s_xw[sc(qr0 + c15, ks * 32 + kq)];

        bf16x8 bfr[4];
        #pragma unroll
        for (int ks = 0; ks < 4; ++ks)
            bfr[ks] = *(const bf16x8*)&qkv_wt[(size_t)c15 * 128 + ks * 32 + kq];
        float bias = qkv_b[c15] * QK_SCALE;

        for (int ct = 0; ct < 24; ++ct) {
            // prefetch next col-tile's b-frags + bias (dummy reload at end)
            const int ctn = (ct < 23) ? ct + 1 : 0;
            const int nn  = ctn * 16 + c15;
            bf16x8 bnx[4];
            #pragma unroll
            for (int ks = 0; ks < 4; ++ks)
                bnx[ks] = *(const bf16x8*)&qkv_wt[(size_t)nn * 128 + ks * 32 + kq];
            const float biasn = qkv_b[nn] * ((ctn < 8) ? QK_SCALE : 1.0f);

            f32x4 ac = (f32x4){0.f, 0.f, 0.f, 0.f};
            #pragma unroll
            for (int ks = 0; ks < 4; ++ks)
                ac = __builtin_amdgcn_mfma_f32_16x16x32_bf16(afr[ks], bfr[ks], ac, 0, 0, 0);

            const int part = ct >> 3;          // 0=Q 1=K 2=V
            const int dc   = (ct & 7) * 16;    // col within part
            #pragma unroll
            for (int r = 0; r < 4; ++r) {
                const int t = qr0 + g * 4 + r;
                const unsigned short hv = f2bf(ac[r] + bias);
                if (part == 0)      s_q [sc(t, dc + c15)] = hv;
                else if (part == 1) s_k [sc(t, dc + c15)] = hv;
                else                s_vt[sc(dc + c15, t)] = hv;  // transposed
            }
            #pragma unroll
            for (int ks = 0; ks < 4; ++ks) bfr[ks] = bnx[ks];
            bias = biasn;
        }
    }

    __syncthreads();   // the only barrier: K/V/rpb become visible cross-wave

    // ---- per-lane head-invariant column info (j = jt*16 + c15) ----
    int colterm[8], rgj[8];
    #pragma unroll
    for (int jt = 0; jt < 8; ++jt) {
        const int j  = jt * 16 + c15;
        const int jh = j >> 5, jw = j & 31;
        colterm[jt] = jh * 63 + jw;
        const int gh1 = wp * WIN_H + jh, gw1 = wq * WIN_W + jw;
        rgj[jt] = ((gh1 < IMG_H - WIN_H) ? 0 : (gh1 < IMG_H - SHIFT_H ? 1 : 2)) * 3
                + ((gw1 < IMG_W - WIN_W) ? 0 : (gw1 < IMG_W - SHIFT_W ? 1 : 2));
    }

    f32x4 acc_out[8];
    #pragma unroll
    for (int n = 0; n < 8; ++n) acc_out[n] = (f32x4){0.f, 0.f, 0.f, 0.f};

    // ---- Phase 2: per head: QK^T -> softmax -> PV -> partial proj ----
    for (int h = 0; h < 4; ++h) {
        bf16x8 bk[8];
        #pragma unroll
        for (int jt = 0; jt < 8; ++jt)
            bk[jt] = *(const bf16x8*)&s_k[sc(jt * 16 + c15, h * 32 + kq)];

        const bf16x8 aq = *(const bf16x8*)&s_q[sc(qr0 + c15, h * 32 + kq)];
        f32x4 sacc[8];
        #pragma unroll
        for (int jt = 0; jt < 8; ++jt)
            sacc[jt] = __builtin_amdgcn_mfma_f32_16x16x32_bf16(
                aq, bk[jt], (f32x4){0.f, 0.f, 0.f, 0.f}, 0, 0, 0);

        // bias + mask + row softmax; rows of this lane: qr0 + g*4 + r
        #pragma unroll
        for (int r = 0; r < 4; ++r) {
            const int q  = qr0 + g * 4 + r;
            const int qh = q >> 5, qw = q & 31;
            const int rowterm = (qh + 3) * 63 + qw + 31;
            const int gh0 = wp * WIN_H + qh, gw0 = wq * WIN_W + qw;
            const int rgq = ((gh0 < IMG_H - WIN_H) ? 0 : (gh0 < IMG_H - SHIFT_H ? 1 : 2)) * 3
                          + ((gw0 < IMG_W - WIN_W) ? 0 : (gw0 < IMG_W - SHIFT_W ? 1 : 2));
            float vals[8];
            float mx = -1e30f;
            #pragma unroll
            for (int jt = 0; jt < 8; ++jt) {
                float a = sacc[jt][r] + s_rpb[(rowterm - colterm[jt]) * 4 + h];
                a = (rgj[jt] != rgq) ? a - 100.f : a;
                vals[jt] = a;
                mx = fmaxf(mx, a);
            }
            #pragma unroll
            for (int off = 1; off < 16; off <<= 1) mx = fmaxf(mx, __shfl_xor(mx, off));
            float den = 0.f;
            #pragma unroll
            for (int jt = 0; jt < 8; ++jt) {
                vals[jt] = exp2f((vals[jt] - mx) * 1.44269504f);
                den += vals[jt];
            }
            #pragma unroll
            for (int off = 1; off < 16; off <<= 1) den += __shfl_xor(den, off);
            const float inv = 1.0f / den;
            #pragma unroll
            for (int jt = 0; jt < 8; ++jt)
                s_xw[sc(q, jt * 16 + c15)] = f2bf(vals[jt] * inv);  // P, wave-private rows
        }

        // PV: O(16x32) = P(16x128) @ V(128x32)
        f32x4 ao[2];
        ao[0] = (f32x4){0.f, 0.f, 0.f, 0.f};
        ao[1] = (f32x4){0.f, 0.f, 0.f, 0.f};
        #pragma unroll
        for (int ks = 0; ks < 4; ++ks) {
            const bf16x8 ap  = *(const bf16x8*)&s_xw[sc(qr0 + c15, ks * 32 + kq)];
            const bf16x8 bv0 = *(const bf16x8*)&s_vt[sc(h * 32 + c15,      ks * 32 + kq)];
            const bf16x8 bv1 = *(const bf16x8*)&s_vt[sc(h * 32 + 16 + c15, ks * 32 + kq)];
            ao[0] = __builtin_amdgcn_mfma_f32_16x16x32_bf16(ap, bv0, ao[0], 0, 0, 0);
            ao[1] = __builtin_amdgcn_mfma_f32_16x16x32_bf16(ap, bv1, ao[1], 0, 0, 0);
        }

        // stage O (bf16) into cols 0..31 of own rows (P fully consumed)
        #pragma unroll
        for (int ct2 = 0; ct2 < 2; ++ct2)
            #pragma unroll
            for (int r = 0; r < 4; ++r)
                s_xw[sc(qr0 + g * 4 + r, ct2 * 16 + c15)] = f2bf(ao[ct2][r]);

        // partial proj: acc_out += O_h(16x32) @ proj_w[h*32..+32][:]
        const bf16x8 aO = *(const bf16x8*)&s_xw[sc(qr0 + c15, kq)];
        #pragma unroll
        for (int ct8 = 0; ct8 < 8; ++ct8) {
            const bf16x8 bw = *(const bf16x8*)&proj_wt[(size_t)(ct8 * 16 + c15) * 128 + h * 32 + kq];
            acc_out[ct8] = __builtin_amdgcn_mfma_f32_16x16x32_bf16(aO, bw, acc_out[ct8], 0, 0, 0);
        }
    }

    // ---- epilogue: out = x + proj(o) + proj_b, reverse shift ----
    #pragma unroll
    for (int ct8 = 0; ct8 < 8; ++ct8) {
        const float pb = proj_b[ct8 * 16 + c15];
        #pragma unroll
        for (int r = 0; r < 4; ++r) {
            const int t  = qr0 + g * 4 + r;
            const int th = t >> 5, tw = t & 31;
            const int gh = (wp * WIN_H + th + SHIFT_H) & (IMG_H - 1);
            const int gw = (wq * WIN_W + tw + SHIFT_W) & (IMG_W - 1);
            const size_t gi = (((size_t)b * IMG_H + gh) * IMG_W + gw) * DIM + ct8 * 16 + c15;
            out[gi] = x[gi] + acc_out[ct8][r] + pb;
        }
    }
}

// ---------------------------------------------------------------------------
// Kernel 2: LN2 + MLP via MFMA. 64 tokens/block, 256 threads (4 waves).
// Changed this round: exact erff GELU -> tanh-form GELU (1 exp2 + rcp).
// ---------------------------------------------------------------------------
__global__ __launch_bounds__(256) void swin_mlp_mfma(
    const float* __restrict__ g2, const float* __restrict__ beta2,
    const unsigned short* __restrict__ w1t,   // [512][128] bf16 (fc1_w^T)
    const float* __restrict__ fc1_b,
    const unsigned short* __restrict__ w2t,   // [128][512] bf16 (fc2_w^T)
    const float* __restrict__ fc2_b,
    float* __restrict__ out)
{
    __shared__ __align__(16) unsigned short s_x[64][136];    // LN'd tokens [m][k]
    __shared__ __align__(16) unsigned short s_h[64][72];     // hidden chunk [m][k]
    __shared__ __align__(16) unsigned short s_w1[64][136];   // w1 chunk B^T [n][k]
    __shared__ __align__(16) unsigned short s_w2[128][72];   // w2 chunk B^T [n][k]

    const int tid = threadIdx.x;
    const int wv  = tid >> 6;
    const int ln  = tid & 63;
    const int m0  = wv * 16;                 // wave-owned token rows
    const size_t tok0 = (size_t)blockIdx.x * 64;

    // ---- LN2: each half-wave handles one token (32 lanes x float4) ----
    {
        const int lh = ln & 31;
        const int hf = ln >> 5;
        const float4 gv = *(const float4*)&g2[lh * 4];
        const float4 bv = *(const float4*)&beta2[lh * 4];
        for (int it = 0; it < 8; ++it) {
            const int t = m0 + it * 2 + hf;
            const float4 v = *(const float4*)&out[(tok0 + t) * 128 + lh * 4];
            float s  = v.x + v.y + v.z + v.w;
            float s2 = v.x * v.x + v.y * v.y + v.z * v.z + v.w * v.w;
            #pragma unroll
            for (int off = 1; off < 32; off <<= 1) {
                s  += __shfl_xor(s, off);
                s2 += __shfl_xor(s2, off);
            }
            const float mean = s * (1.0f / 128.0f);
            const float var  = s2 * (1.0f / 128.0f) - mean * mean;
            const float rs   = rsqrtf(var + 1e-5f);
            const unsigned short o0 = f2bf((v.x - mean) * rs * gv.x + bv.x);
            const unsigned short o1 = f2bf((v.y - mean) * rs * gv.y + bv.y);
            const unsigned short o2 = f2bf((v.z - mean) * rs * gv.z + bv.z);
            const unsigned short o3 = f2bf((v.w - mean) * rs * gv.w + bv.w);
            uint2 pk;
            pk.x = (unsigned)o0 | ((unsigned)o1 << 16);
            pk.y = (unsigned)o2 | ((unsigned)o3 << 16);
            *(uint2*)&s_x[t][lh * 4] = pk;
        }
    }

    f32x4 acc_o[8];
    #pragma unroll
    for (int i = 0; i < 8; ++i) acc_o[i] = (f32x4){0.f, 0.f, 0.f, 0.f};

    const int ar = m0 + (ln & 15);          // a-frag row
    const int nr = ln & 15;                 // b-frag n within tile
    const int kq = (ln >> 4) * 8;           // k quad offset
    const int dr = m0 + (ln >> 4) * 4;      // D-frag row base

    for (int c = 0; c < 8; ++c) {
        for (int j = tid; j < 1024; j += 256) {
            const int row = j >> 4, c8 = j & 15;
            *(uint4*)&s_w1[row][c8 * 8] = *(const uint4*)&w1t[(size_t)(c * 64 + row) * 128 + c8 * 8];
        }
        for (int j = tid; j < 1024; j += 256) {
            const int row = j >> 3, c8 = j & 7;
            *(uint4*)&s_w2[row][c8 * 8] = *(const uint4*)&w2t[(size_t)row * 512 + c * 64 + c8 * 8];
        }
        __syncthreads();
        // GEMM1: h(16x64 per wave) = x_ln(16x128) @ w1c(128x64)
        f32x4 hA[4];
        #pragma unroll
        for (int i = 0; i < 4; ++i) hA[i] = (f32x4){0.f, 0.f, 0.f, 0.f};
        #pragma unroll
        for (int ks = 0; ks < 4; ++ks) {
            const bf16x8 a = *(const bf16x8*)&s_x[ar][ks * 32 + kq];
            #pragma unroll
            for (int nt = 0; nt < 4; ++nt) {
                const bf16x8 bb = *(const bf16x8*)&s_w1[nt * 16 + nr][ks * 32 + kq];
                hA[nt] = __builtin_amdgcn_mfma_f32_16x16x32_bf16(a, bb, hA[nt], 0, 0, 0);
            }
        }
        // bias + tanh-GELU, write hidden chunk (wave-private rows)
        #pragma unroll
        for (int nt = 0; nt < 4; ++nt) {
            const float bias = fc1_b[c * 64 + nt * 16 + nr];
            #pragma unroll
            for (int r = 0; r < 4; ++r) {
                const float v = hA[nt][r] + bias;
                s_h[dr + r][nt * 16 + nr] = f2bf(gelu_tanh(v));
            }
        }
        __syncthreads();
        // GEMM2: acc_o += h(16x64) @ w2c(64x128)
        #pragma unroll
        for (int ks = 0; ks < 2; ++ks) {
            const bf16x8 a = *(const bf16x8*)&s_h[ar][ks * 32 + kq];
            #pragma unroll
            for (int nt = 0; nt < 8; ++nt) {
                const bf16x8 bb = *(const bf16x8*)&s_w2[nt * 16 + nr][ks * 32 + kq];
                acc_o[nt] = __builtin_amdgcn_mfma_f32_16x16x32_bf16(a, bb, acc_o[nt], 0, 0, 0);
            }
        }
        __syncthreads();
    }

    // ---- epilogue: out += mlp(out_ln) + fc2_b  (residual re-read, L2-hot) ----
    #pragma unroll
    for (int nt = 0; nt < 8; ++nt) {
        const float bias = fc2_b[nt * 16 + nr];
        #pragma unroll
        for (int r = 0; r < 4; ++r) {
            const size_t gi = (tok0 + dr + r) * 128 + nt * 16 + nr;
            out[gi] = out[gi] + acc_o[nt][r] + bias;
        }
    }
}

extern "C" void kernel_launch(void* const* d_in, const int* in_sizes, int n_in,
                              void* d_out, int out_size, void* d_ws, size_t ws_size,
                              hipStream_t stream) {
    (void)in_sizes; (void)n_in; (void)out_size;
    const float* x      = (const float*)d_in[0];
    const float* g1     = (const float*)d_in[1];
    const float* b1     = (const float*)d_in[2];
    const float* qkv_w  = (const float*)d_in[3];
    const float* qkv_b  = (const float*)d_in[4];
    const float* rpb    = (const float*)d_in[5];
    const float* proj_w = (const float*)d_in[6];
    const float* proj_b = (const float*)d_in[7];
    const float* g2     = (const float*)d_in[8];
    const float* bb2    = (const float*)d_in[9];
    const float* fc1_w  = (const float*)d_in[10];
    const float* fc1_b  = (const float*)d_in[11];
    const float* fc2_w  = (const float*)d_in[12];
    const float* fc2_b  = (const float*)d_in[13];

    // Workspace layout (bf16 shorts): w1t | w2t | qkv_wt | proj_wt
    const size_t ws_needed = (size_t)(2 * 512 * 128 + 384 * 128 + 128 * 128)
                           * sizeof(unsigned short);   // 384 KiB
    if (ws_size != 0 && ws_size < ws_needed) {
        return;   // fail cleanly instead of corrupting memory
    }

    unsigned short* w1t     = (unsigned short*)d_ws;             // 512*128 bf16
    unsigned short* w2t     = w1t + 512 * 128;                   // 128*512 bf16
    unsigned short* qkv_wt  = w2t + 512 * 128;                   // 384*128 bf16
    unsigned short* proj_wt = qkv_wt + 384 * 128;                // 128*128 bf16

    hipLaunchKernelGGL(prep_weights, dim3(768), dim3(256), 0, stream,
                       fc1_w, fc2_w, qkv_w, proj_w, w1t, w2t, qkv_wt, proj_wt);
    hipLaunchKernelGGL(swin_attn_mfma, dim3(BATCH * 256), dim3(512), 0, stream,
                       x, g1, b1, qkv_wt, qkv_b, rpb, proj_wt, proj_b, (float*)d_out);
    hipLaunchKernelGGL(swin_mlp_mfma, dim3(BATCH * IMG_H * IMG_W / 64), dim3(256), 0, stream,
                       g2, bb2, w1t, fc1_b, w2t, fc2_b, (float*)d_out);
}

// Round 6
// 738.254 us; speedup vs baseline: 5.3676x; 1.1355x over previous
//
#include <hip/hip_runtime.h>
#include <hip/hip_bf16.h>
#include <math.h>

constexpr int BATCH = 8;
constexpr int IMG_H = 64;
constexpr int IMG_W = 512;
constexpr int DIM   = 128;
constexpr int WIN_H = 4, WIN_W = 32;
constexpr int SHIFT_H = 2, SHIFT_W = 2;
constexpr int NTOK = 128;            // tokens per window
constexpr int HEADS = 4, HD = 32;
constexpr float QK_SCALE = 0.17677669529663687f;   // 1/sqrt(32)

typedef __attribute__((ext_vector_type(8))) short bf16x8;
typedef __attribute__((ext_vector_type(4))) float f32x4;

__device__ __forceinline__ unsigned short f2bf(float f) {
    unsigned u = __float_as_uint(f);
    u = (u + 0x7fffu + ((u >> 16) & 1u)) >> 16;   // RNE
    return (unsigned short)u;
}

// XOR-swizzled index into a [128][128] bf16 LDS tile (T2, breaks the
// stride-256B 32-way bank conflict on ds_read_b128). 16B-chunk safe.
__device__ __forceinline__ int sc(int r, int c) {
    return (r << 7) + (c ^ ((r & 7) << 3));
}

// tanh-form GELU: max |err| vs exact erf-GELU ~4e-4 -> below bf16 rounding.
__device__ __forceinline__ float gelu_tanh(float v) {
    const float u = v * (0.7978845608028654f + 0.035677408136300125f * v * v);
    const float e = exp2f(u * -2.8853900817779268f);   // exp(-2u)
    return v * __builtin_amdgcn_rcpf(1.0f + e);
}

// ---------------------------------------------------------------------------
// Kernel 0: convert weights to bf16, transposed (B^T layout for b-frags).
// ---------------------------------------------------------------------------
__global__ __launch_bounds__(256) void prep_weights(
    const float* __restrict__ fc1_w, const float* __restrict__ fc2_w,
    const float* __restrict__ qkv_w, const float* __restrict__ proj_w,
    unsigned short* __restrict__ w1t, unsigned short* __restrict__ w2t,
    unsigned short* __restrict__ qkv_wt, unsigned short* __restrict__ proj_wt)
{
    const int tid = blockIdx.x * 256 + threadIdx.x;
    if (tid < 512 * 128) {
        const int n = tid >> 7, k = tid & 127;
        w1t[tid] = f2bf(fc1_w[k * 512 + n]);
    } else if (tid < 2 * 512 * 128) {
        const int t = tid - 512 * 128;
        const int n = t >> 9, k = t & 511;
        w2t[t] = f2bf(fc2_w[k * 128 + n]);
    } else if (tid < 2 * 512 * 128 + 384 * 128) {
        const int t = tid - 2 * 512 * 128;
        const int n = t >> 7, k = t & 127;
        float v = qkv_w[k * 384 + n];
        if (n < 128) v *= QK_SCALE;      // fold softmax scale into Wq
        qkv_wt[t] = f2bf(v);
    } else if (tid < 2 * 512 * 128 + 384 * 128 + 128 * 128) {
        const int t = tid - (2 * 512 * 128 + 384 * 128);
        const int n = t >> 7, k = t & 127;
        proj_wt[t] = f2bf(proj_w[k * 128 + n]);
    }
}

// ---------------------------------------------------------------------------
// Kernel 1: LN1 + cyclic shift + window attention + proj + residual, MFMA.
// PROVEN round-3 version: 512 threads = 8 waves (2 waves/SIMD), wave wv owns
// token rows 16*wv..+15 end-to-end -> one __syncthreads().
// ---------------------------------------------------------------------------
__global__ __launch_bounds__(512, 2) void swin_attn_mfma(
    const float* __restrict__ x,
    const float* __restrict__ g1,
    const float* __restrict__ b1,
    const unsigned short* __restrict__ qkv_wt,   // [384][128] bf16 (Q scaled)
    const float* __restrict__ qkv_b,
    const float* __restrict__ rpb,
    const unsigned short* __restrict__ proj_wt,  // [128][128] bf16
    const float* __restrict__ proj_b,
    float* __restrict__ out)
{
    __shared__ __align__(16) unsigned short s_xw[128 * 128]; // LN'd x; later P/O scratch
    __shared__ __align__(16) unsigned short s_q [128 * 128]; // Q (scaled) [t][d]
    __shared__ __align__(16) unsigned short s_k [128 * 128]; // K [t][d]
    __shared__ __align__(16) unsigned short s_vt[128 * 128]; // V^T [d][t]
    __shared__ float s_rpb[441 * 4];

    const int tid = threadIdx.x;
    const int wv  = tid >> 6;         // 0..7
    const int ln  = tid & 63;
    const int g   = ln >> 4;          // 0..3
    const int c15 = ln & 15;          // frag row/col lane index
    const int kq  = g * 8;            // k offset (shorts) for a/b frags
    const int qr0 = wv * 16;          // wave-owned token rows (16 each)

    const int b   = blockIdx.x >> 8;
    const int wid = blockIdx.x & 255;
    const int wp  = wid >> 4;
    const int wq  = wid & 15;

    // ---- Phase 0: LN1 + shift -> s_xw (bf16). Half-wave per token. ----
    {
        const int lh = ln & 31;
        const int hf = ln >> 5;
        const float4 gv = *(const float4*)&g1[lh * 4];
        const float4 bv = *(const float4*)&b1[lh * 4];
        #pragma unroll
        for (int it = 0; it < 8; ++it) {
            const int t  = qr0 + it * 2 + hf;
            const int th = t >> 5, tw = t & 31;
            const int gh = (wp * WIN_H + th + SHIFT_H) & (IMG_H - 1);
            const int gw = (wq * WIN_W + tw + SHIFT_W) & (IMG_W - 1);
            const float4 v = *(const float4*)&x[((((size_t)b * IMG_H + gh) * IMG_W + gw) * DIM) + lh * 4];
            float s  = v.x + v.y + v.z + v.w;
            float s2 = v.x * v.x + v.y * v.y + v.z * v.z + v.w * v.w;
            #pragma unroll
            for (int off = 1; off < 32; off <<= 1) {
                s  += __shfl_xor(s, off);
                s2 += __shfl_xor(s2, off);
            }
            const float mean = s * (1.0f / 128.0f);
            const float rs   = rsqrtf(s2 * (1.0f / 128.0f) - mean * mean + 1e-5f);
            const unsigned short o0 = f2bf((v.x - mean) * rs * gv.x + bv.x);
            const unsigned short o1 = f2bf((v.y - mean) * rs * gv.y + bv.y);
            const unsigned short o2 = f2bf((v.z - mean) * rs * gv.z + bv.z);
            const unsigned short o3 = f2bf((v.w - mean) * rs * gv.w + bv.w);
            uint2 pk;
            pk.x = (unsigned)o0 | ((unsigned)o1 << 16);
            pk.y = (unsigned)o2 | ((unsigned)o3 << 16);
            *(uint2*)&s_xw[sc(t, lh * 4)] = pk;
        }
    }

    // stage rpb (all heads) into LDS (covered by the single barrier below)
    for (int i = tid; i < 441 * 4; i += 512) s_rpb[i] = rpb[i];

    // ---- Phase 1: QKV = xw @ Wqkv. Wave computes its 16 rows x all 384. ----
    {
        bf16x8 afr[4];
        #pragma unroll
        for (int ks = 0; ks < 4; ++ks)
            afr[ks] = *(const bf16x8*)&s_xw[sc(qr0 + c15, ks * 32 + kq)];

        bf16x8 bfr[4];
        #pragma unroll
        for (int ks = 0; ks < 4; ++ks)
            bfr[ks] = *(const bf16x8*)&qkv_wt[(size_t)c15 * 128 + ks * 32 + kq];
        float bias = qkv_b[c15] * QK_SCALE;

        for (int ct = 0; ct < 24; ++ct) {
            // prefetch next col-tile's b-frags + bias (dummy reload at end)
            const int ctn = (ct < 23) ? ct + 1 : 0;
            const int nn  = ctn * 16 + c15;
            bf16x8 bnx[4];
            #pragma unroll
            for (int ks = 0; ks < 4; ++ks)
                bnx[ks] = *(const bf16x8*)&qkv_wt[(size_t)nn * 128 + ks * 32 + kq];
            const float biasn = qkv_b[nn] * ((ctn < 8) ? QK_SCALE : 1.0f);

            f32x4 ac = (f32x4){0.f, 0.f, 0.f, 0.f};
            #pragma unroll
            for (int ks = 0; ks < 4; ++ks)
                ac = __builtin_amdgcn_mfma_f32_16x16x32_bf16(afr[ks], bfr[ks], ac, 0, 0, 0);

            const int part = ct >> 3;          // 0=Q 1=K 2=V
            const int dc   = (ct & 7) * 16;    // col within part
            #pragma unroll
            for (int r = 0; r < 4; ++r) {
                const int t = qr0 + g * 4 + r;
                const unsigned short hv = f2bf(ac[r] + bias);
                if (part == 0)      s_q [sc(t, dc + c15)] = hv;
                else if (part == 1) s_k [sc(t, dc + c15)] = hv;
                else                s_vt[sc(dc + c15, t)] = hv;  // transposed
            }
            #pragma unroll
            for (int ks = 0; ks < 4; ++ks) bfr[ks] = bnx[ks];
            bias = biasn;
        }
    }

    __syncthreads();   // the only barrier: K/V/rpb become visible cross-wave

    // ---- per-lane head-invariant column info (j = jt*16 + c15) ----
    int colterm[8], rgj[8];
    #pragma unroll
    for (int jt = 0; jt < 8; ++jt) {
        const int j  = jt * 16 + c15;
        const int jh = j >> 5, jw = j & 31;
        colterm[jt] = jh * 63 + jw;
        const int gh1 = wp * WIN_H + jh, gw1 = wq * WIN_W + jw;
        rgj[jt] = ((gh1 < IMG_H - WIN_H) ? 0 : (gh1 < IMG_H - SHIFT_H ? 1 : 2)) * 3
                + ((gw1 < IMG_W - WIN_W) ? 0 : (gw1 < IMG_W - SHIFT_W ? 1 : 2));
    }

    f32x4 acc_out[8];
    #pragma unroll
    for (int n = 0; n < 8; ++n) acc_out[n] = (f32x4){0.f, 0.f, 0.f, 0.f};

    // ---- Phase 2: per head: QK^T -> softmax -> PV -> partial proj ----
    for (int h = 0; h < 4; ++h) {
        bf16x8 bk[8];
        #pragma unroll
        for (int jt = 0; jt < 8; ++jt)
            bk[jt] = *(const bf16x8*)&s_k[sc(jt * 16 + c15, h * 32 + kq)];

        const bf16x8 aq = *(const bf16x8*)&s_q[sc(qr0 + c15, h * 32 + kq)];
        f32x4 sacc[8];
        #pragma unroll
        for (int jt = 0; jt < 8; ++jt)
            sacc[jt] = __builtin_amdgcn_mfma_f32_16x16x32_bf16(
                aq, bk[jt], (f32x4){0.f, 0.f, 0.f, 0.f}, 0, 0, 0);

        // bias + mask + row softmax; rows of this lane: qr0 + g*4 + r
        #pragma unroll
        for (int r = 0; r < 4; ++r) {
            const int q  = qr0 + g * 4 + r;
            const int qh = q >> 5, qw = q & 31;
            const int rowterm = (qh + 3) * 63 + qw + 31;
            const int gh0 = wp * WIN_H + qh, gw0 = wq * WIN_W + qw;
            const int rgq = ((gh0 < IMG_H - WIN_H) ? 0 : (gh0 < IMG_H - SHIFT_H ? 1 : 2)) * 3
                          + ((gw0 < IMG_W - WIN_W) ? 0 : (gw0 < IMG_W - SHIFT_W ? 1 : 2));
            float vals[8];
            float mx = -1e30f;
            #pragma unroll
            for (int jt = 0; jt < 8; ++jt) {
                float a = sacc[jt][r] + s_rpb[(rowterm - colterm[jt]) * 4 + h];
                a = (rgj[jt] != rgq) ? a - 100.f : a;
                vals[jt] = a;
                mx = fmaxf(mx, a);
            }
            #pragma unroll
            for (int off = 1; off < 16; off <<= 1) mx = fmaxf(mx, __shfl_xor(mx, off));
            float den = 0.f;
            #pragma unroll
            for (int jt = 0; jt < 8; ++jt) {
                vals[jt] = exp2f((vals[jt] - mx) * 1.44269504f);
                den += vals[jt];
            }
            #pragma unroll
            for (int off = 1; off < 16; off <<= 1) den += __shfl_xor(den, off);
            const float inv = 1.0f / den;
            #pragma unroll
            for (int jt = 0; jt < 8; ++jt)
                s_xw[sc(q, jt * 16 + c15)] = f2bf(vals[jt] * inv);  // P, wave-private rows
        }

        // PV: O(16x32) = P(16x128) @ V(128x32)
        f32x4 ao[2];
        ao[0] = (f32x4){0.f, 0.f, 0.f, 0.f};
        ao[1] = (f32x4){0.f, 0.f, 0.f, 0.f};
        #pragma unroll
        for (int ks = 0; ks < 4; ++ks) {
            const bf16x8 ap  = *(const bf16x8*)&s_xw[sc(qr0 + c15, ks * 32 + kq)];
            const bf16x8 bv0 = *(const bf16x8*)&s_vt[sc(h * 32 + c15,      ks * 32 + kq)];
            const bf16x8 bv1 = *(const bf16x8*)&s_vt[sc(h * 32 + 16 + c15, ks * 32 + kq)];
            ao[0] = __builtin_amdgcn_mfma_f32_16x16x32_bf16(ap, bv0, ao[0], 0, 0, 0);
            ao[1] = __builtin_amdgcn_mfma_f32_16x16x32_bf16(ap, bv1, ao[1], 0, 0, 0);
        }

        // stage O (bf16) into cols 0..31 of own rows (P fully consumed)
        #pragma unroll
        for (int ct2 = 0; ct2 < 2; ++ct2)
            #pragma unroll
            for (int r = 0; r < 4; ++r)
                s_xw[sc(qr0 + g * 4 + r, ct2 * 16 + c15)] = f2bf(ao[ct2][r]);

        // partial proj: acc_out += O_h(16x32) @ proj_w[h*32..+32][:]
        const bf16x8 aO = *(const bf16x8*)&s_xw[sc(qr0 + c15, kq)];
        #pragma unroll
        for (int ct8 = 0; ct8 < 8; ++ct8) {
            const bf16x8 bw = *(const bf16x8*)&proj_wt[(size_t)(ct8 * 16 + c15) * 128 + h * 32 + kq];
            acc_out[ct8] = __builtin_amdgcn_mfma_f32_16x16x32_bf16(aO, bw, acc_out[ct8], 0, 0, 0);
        }
    }

    // ---- epilogue: out = x + proj(o) + proj_b, reverse shift ----
    #pragma unroll
    for (int ct8 = 0; ct8 < 8; ++ct8) {
        const float pb = proj_b[ct8 * 16 + c15];
        #pragma unroll
        for (int r = 0; r < 4; ++r) {
            const int t  = qr0 + g * 4 + r;
            const int th = t >> 5, tw = t & 31;
            const int gh = (wp * WIN_H + th + SHIFT_H) & (IMG_H - 1);
            const int gw = (wq * WIN_W + tw + SHIFT_W) & (IMG_W - 1);
            const size_t gi = (((size_t)b * IMG_H + gh) * IMG_W + gw) * DIM + ct8 * 16 + c15;
            out[gi] = x[gi] + acc_out[ct8][r] + pb;
        }
    }
}

// ---------------------------------------------------------------------------
// Kernel 2: LN2 + MLP via MFMA. 64 tokens/block, 512 threads (8 waves),
// wave pair (rg, ch): rg owns 16 token rows; ch splits hidden cols (GEMM1)
// and output cols (GEMM2). LDS ~62 KB -> 2 blocks/CU -> 16 waves/CU.
// ---------------------------------------------------------------------------
__global__ __launch_bounds__(512, 4) void swin_mlp_mfma(
    const float* __restrict__ g2, const float* __restrict__ beta2,
    const unsigned short* __restrict__ w1t,   // [512][128] bf16 (fc1_w^T)
    const float* __restrict__ fc1_b,
    const unsigned short* __restrict__ w2t,   // [128][512] bf16 (fc2_w^T)
    const float* __restrict__ fc2_b,
    float* __restrict__ out)
{
    __shared__ __align__(16) unsigned short s_x[64][136];    // LN'd tokens [m][k]
    __shared__ __align__(16) unsigned short s_h[64][72];     // hidden chunk [m][k]
    __shared__ __align__(16) unsigned short s_w1[64][136];   // w1 chunk B^T [n][k]
    __shared__ __align__(16) unsigned short s_w2[128][72];   // w2 chunk B^T [n][k]

    const int tid = threadIdx.x;
    const int wv  = tid >> 6;               // 0..7
    const int ln  = tid & 63;
    const int rg  = wv >> 1;                // 0..3: 16 token rows each
    const int ch  = wv & 1;                 // column half
    const int m0  = rg * 16;
    const size_t tok0 = (size_t)blockIdx.x * 64;

    // ---- LN2: half-wave per token; 16 half-waves x 4 iters = 64 tokens ----
    {
        const int lh = tid & 31;
        const int hw = tid >> 5;            // 0..15
        const float4 gv = *(const float4*)&g2[lh * 4];
        const float4 bv = *(const float4*)&beta2[lh * 4];
        #pragma unroll
        for (int it = 0; it < 4; ++it) {
            const int t = it * 16 + hw;
            const float4 v = *(const float4*)&out[(tok0 + t) * 128 + lh * 4];
            float s  = v.x + v.y + v.z + v.w;
            float s2 = v.x * v.x + v.y * v.y + v.z * v.z + v.w * v.w;
            #pragma unroll
            for (int off = 1; off < 32; off <<= 1) {
                s  += __shfl_xor(s, off);
                s2 += __shfl_xor(s2, off);
            }
            const float mean = s * (1.0f / 128.0f);
            const float rs   = rsqrtf(s2 * (1.0f / 128.0f) - mean * mean + 1e-5f);
            const unsigned short o0 = f2bf((v.x - mean) * rs * gv.x + bv.x);
            const unsigned short o1 = f2bf((v.y - mean) * rs * gv.y + bv.y);
            const unsigned short o2 = f2bf((v.z - mean) * rs * gv.z + bv.z);
            const unsigned short o3 = f2bf((v.w - mean) * rs * gv.w + bv.w);
            uint2 pk;
            pk.x = (unsigned)o0 | ((unsigned)o1 << 16);
            pk.y = (unsigned)o2 | ((unsigned)o3 << 16);
            *(uint2*)&s_x[t][lh * 4] = pk;
        }
    }

    f32x4 acc_o[4];
    #pragma unroll
    for (int i = 0; i < 4; ++i) acc_o[i] = (f32x4){0.f, 0.f, 0.f, 0.f};

    const int ar = m0 + (ln & 15);          // a-frag row
    const int nr = ln & 15;                 // b-frag n within tile
    const int kq = (ln >> 4) * 8;           // k quad offset
    const int dr = m0 + (ln >> 4) * 4;      // D-frag row base

    for (int c = 0; c < 8; ++c) {
        for (int j = tid; j < 1024; j += 512) {
            const int row = j >> 4, c8 = j & 15;
            *(uint4*)&s_w1[row][c8 * 8] = *(const uint4*)&w1t[(size_t)(c * 64 + row) * 128 + c8 * 8];
        }
        for (int j = tid; j < 1024; j += 512) {
            const int row = j >> 3, c8 = j & 7;
            *(uint4*)&s_w2[row][c8 * 8] = *(const uint4*)&w2t[(size_t)row * 512 + c * 64 + c8 * 8];
        }
        __syncthreads();
        // GEMM1: h(16 x 32 per wave) = x_ln(16x128) @ w1c slice
        f32x4 hA[2];
        hA[0] = (f32x4){0.f, 0.f, 0.f, 0.f};
        hA[1] = (f32x4){0.f, 0.f, 0.f, 0.f};
        #pragma unroll
        for (int ks = 0; ks < 4; ++ks) {
            const bf16x8 a = *(const bf16x8*)&s_x[ar][ks * 32 + kq];
            #pragma unroll
            for (int n2 = 0; n2 < 2; ++n2) {
                const int nt = ch * 2 + n2;
                const bf16x8 bb = *(const bf16x8*)&s_w1[nt * 16 + nr][ks * 32 + kq];
                hA[n2] = __builtin_amdgcn_mfma_f32_16x16x32_bf16(a, bb, hA[n2], 0, 0, 0);
            }
        }
        // bias + tanh-GELU, write hidden slice
        #pragma unroll
        for (int n2 = 0; n2 < 2; ++n2) {
            const int nt = ch * 2 + n2;
            const float bias = fc1_b[c * 64 + nt * 16 + nr];
            #pragma unroll
            for (int r = 0; r < 4; ++r) {
                const float v = hA[n2][r] + bias;
                s_h[dr + r][nt * 16 + nr] = f2bf(gelu_tanh(v));
            }
        }
        __syncthreads();
        // GEMM2: acc_o += h(16x64) @ w2c slice (output cols ch*64..+63)
        #pragma unroll
        for (int ks = 0; ks < 2; ++ks) {
            const bf16x8 a = *(const bf16x8*)&s_h[ar][ks * 32 + kq];
            #pragma unroll
            for (int n2 = 0; n2 < 4; ++n2) {
                const int nt = ch * 4 + n2;
                const bf16x8 bb = *(const bf16x8*)&s_w2[nt * 16 + nr][ks * 32 + kq];
                acc_o[n2] = __builtin_amdgcn_mfma_f32_16x16x32_bf16(a, bb, acc_o[n2], 0, 0, 0);
            }
        }
        __syncthreads();
    }

    // ---- epilogue: out += mlp(out_ln) + fc2_b ----
    #pragma unroll
    for (int n2 = 0; n2 < 4; ++n2) {
        const int nt = ch * 4 + n2;
        const float bias = fc2_b[nt * 16 + nr];
        #pragma unroll
        for (int r = 0; r < 4; ++r) {
            const size_t gi = (tok0 + dr + r) * 128 + nt * 16 + nr;
            out[gi] = out[gi] + acc_o[n2][r] + bias;
        }
    }
}

extern "C" void kernel_launch(void* const* d_in, const int* in_sizes, int n_in,
                              void* d_out, int out_size, void* d_ws, size_t ws_size,
                              hipStream_t stream) {
    (void)in_sizes; (void)n_in; (void)out_size;
    const float* x      = (const float*)d_in[0];
    const float* g1     = (const float*)d_in[1];
    const float* b1     = (const float*)d_in[2];
    const float* qkv_w  = (const float*)d_in[3];
    const float* qkv_b  = (const float*)d_in[4];
    const float* rpb    = (const float*)d_in[5];
    const float* proj_w = (const float*)d_in[6];
    const float* proj_b = (const float*)d_in[7];
    const float* g2     = (const float*)d_in[8];
    const float* bb2    = (const float*)d_in[9];
    const float* fc1_w  = (const float*)d_in[10];
    const float* fc1_b  = (const float*)d_in[11];
    const float* fc2_w  = (const float*)d_in[12];
    const float* fc2_b  = (const float*)d_in[13];

    // Workspace layout (bf16 shorts): w1t | w2t | qkv_wt | proj_wt
    const size_t ws_needed = (size_t)(2 * 512 * 128 + 384 * 128 + 128 * 128)
                           * sizeof(unsigned short);   // 384 KiB
    if (ws_size != 0 && ws_size < ws_needed) {
        return;   // fail cleanly instead of corrupting memory
    }

    unsigned short* w1t     = (unsigned short*)d_ws;             // 512*128 bf16
    unsigned short* w2t     = w1t + 512 * 128;                   // 128*512 bf16
    unsigned short* qkv_wt  = w2t + 512 * 128;                   // 384*128 bf16
    unsigned short* proj_wt = qkv_wt + 384 * 128;                // 128*128 bf16

    hipLaunchKernelGGL(prep_weights, dim3(768), dim3(256), 0, stream,
                       fc1_w, fc2_w, qkv_w, proj_w, w1t, w2t, qkv_wt, proj_wt);
    hipLaunchKernelGGL(swin_attn_mfma, dim3(BATCH * 256), dim3(512), 0, stream,
                       x, g1, b1, qkv_wt, qkv_b, rpb, proj_wt, proj_b, (float*)d_out);
    hipLaunchKernelGGL(swin_mlp_mfma, dim3(BATCH * IMG_H * IMG_W / 64), dim3(512), 0, stream,
                       g2, bb2, w1t, fc1_b, w2t, fc2_b, (float*)d_out);
}